// Round 10
// baseline (337.744 us; speedup 1.0000x reference)
//
#include <hip/hip_runtime.h>

#define N_NODES 100000
#define N_EDGES 1200000
#define N_GRAPHS 256
#define NBUCK 392            // buckets of 256 nodes: 392*256 = 100352 >= N
#define EBLK 98              // edge-pass blocks
#define EPB 12245            // ceil(E/98)
#define DCAP 4608            // max edges per bucket handled in LDS (mean 3072, sd 55)

typedef __attribute__((ext_vector_type(8))) short bf16x8;
typedef __attribute__((ext_vector_type(4))) float f32x4;

// ---- bf16 helpers (fp32 <-> bf16 as ushort, RNE) ----
__device__ inline unsigned short f2b(float f) {
    union { float f; unsigned u; } c; c.f = f;
    unsigned u = c.u;
    u += 0x7fff + ((u >> 16) & 1);
    return (unsigned short)(u >> 16);
}
__device__ inline float blo(unsigned u) { union { unsigned i; float f; } c; c.i = u << 16; return c.f; }
__device__ inline float bhi(unsigned u) { union { unsigned i; float f; } c; c.i = u & 0xffff0000u; return c.f; }
__device__ inline float b2f(unsigned short h) { union { unsigned i; float f; } c; c.i = ((unsigned)h) << 16; return c.f; }

// ---------------- bucket phase A: per-(bucket, block) histogram ----------------
__global__ __launch_bounds__(256) void bucketA(const int* __restrict__ ei, int* __restrict__ histm) {
    __shared__ int h[NBUCK];
    int k = blockIdx.x, tid = threadIdx.x;
    for (int t = tid; t < NBUCK; t += 256) h[t] = 0;
    __syncthreads();
    int e0 = k * EPB, e1 = min(e0 + EPB, N_EDGES);
    for (int e = e0 + tid; e < e1; e += 256) {
        int dd = ei[N_EDGES + e];
        atomicAdd(&h[dd >> 8], 1);
    }
    __syncthreads();
    for (int t = tid; t < NBUCK; t += 256) histm[t * EBLK + k] = h[t];
}

// ---------------- phase B: scan histm -> per-(bucket,block) start offsets + bucket starts ----------------
__global__ __launch_bounds__(512) void bucketB(int* __restrict__ histm, int* __restrict__ bstart) {
    __shared__ int sb[512];
    int tid = threadIdx.x;
    int tot = 0;
    if (tid < NBUCK) {
        for (int k = 0; k < EBLK; k++) tot += histm[tid * EBLK + k];
    }
    sb[tid] = tot;
    __syncthreads();
    int acc = tot;
    for (int off = 1; off < 512; off <<= 1) {
        int v = (tid >= off) ? sb[tid - off] : 0;
        __syncthreads();
        sb[tid] = acc = acc + v;
        __syncthreads();
    }
    int excl = acc - tot;
    if (tid < NBUCK) {
        bstart[tid] = excl;
        int run = excl;
        for (int k = 0; k < EBLK; k++) {
            int v = histm[tid * EBLK + k];
            histm[tid * EBLK + k] = run;
            run += v;
        }
    }
    if (tid == 0) bstart[NBUCK] = N_EDGES;
}

// ---------------- phase C: scatter packed (src<<8 | dstlow) into bucket-grouped ebuf ----------------
__global__ __launch_bounds__(256) void bucketC(const int* __restrict__ ei, const int* __restrict__ histm,
                                               int* __restrict__ ebuf) {
    __shared__ int cur[NBUCK];
    int k = blockIdx.x, tid = threadIdx.x;
    for (int t = tid; t < NBUCK; t += 256) cur[t] = histm[t * EBLK + k];
    __syncthreads();
    int e0 = k * EPB, e1 = min(e0 + EPB, N_EDGES);
    for (int e = e0 + tid; e < e1; e += 256) {
        int ss = ei[e];
        int dd = ei[N_EDGES + e];
        int pos = atomicAdd(&cur[dd >> 8], 1);
        ebuf[pos] = (ss << 8) | (dd & 255);
    }
}

// ---------------- phase D: per-bucket counting sort -> rowptr + esrc (coalesced writes) ----------------
__global__ __launch_bounds__(256) void bucketD(const int* __restrict__ ebuf, const int* __restrict__ bstart,
                                               int* __restrict__ rowptr, int* __restrict__ esrc) {
    __shared__ int ecache[DCAP];
    __shared__ int stage[DCAP];
    __shared__ int hist[256], off[256];
    int b = blockIdx.x, tid = threadIdx.x;
    int seg0 = bstart[b], seg1 = bstart[b + 1];
    int cnt = seg1 - seg0;
    hist[tid] = 0;
    int lim = min(cnt, DCAP);
    for (int i = tid; i < lim; i += 256) ecache[i] = ebuf[seg0 + i];
    __syncthreads();
    for (int i = tid; i < cnt; i += 256) {
        int p = (i < DCAP) ? ecache[i] : ebuf[seg0 + i];
        atomicAdd(&hist[p & 255], 1);
    }
    __syncthreads();
    int v = hist[tid];
    off[tid] = v;
    __syncthreads();
    int acc = v;
    for (int o = 1; o < 256; o <<= 1) {
        int t = (tid >= o) ? off[tid - o] : 0;
        __syncthreads();
        off[tid] = acc = acc + t;
        __syncthreads();
    }
    int excl = acc - v;
    rowptr[b * 256 + tid] = seg0 + excl;
    off[tid] = excl;
    __syncthreads();
    if (cnt <= DCAP) {
        for (int i = tid; i < cnt; i += 256) {
            int p = ecache[i];
            int pos = atomicAdd(&off[p & 255], 1);
            stage[pos] = (p >> 8) << 7;    // pre-scaled byte offset (bf16 64-dim row = 128 B)
        }
        __syncthreads();
        for (int i = tid; i < cnt; i += 256) esrc[seg0 + i] = stage[i];
    } else {                               // correctness fallback, never in practice
        for (int i = tid; i < cnt; i += 256) {
            int p = (i < DCAP) ? ecache[i] : ebuf[seg0 + i];
            int pos = atomicAdd(&off[p & 255], 1);
            esrc[seg0 + pos] = (p >> 8) << 7;
        }
    }
}

// ---------------- prepack W' = [W2l;W2r] (128x64) into MFMA B-fragment order, bf16 ----------------
__global__ __launch_bounds__(256) void prepack_kernel(const float* __restrict__ W2l, const float* __restrict__ W2r,
                                                      unsigned short* __restrict__ pw2) {
    int r = blockIdx.x * 256 + threadIdx.x;    // 8192 total
    int j = r & 7, lane = (r >> 3) & 63, t = (r >> 9) & 3, s = (r >> 11) & 3;
    int k = s * 32 + (lane >> 4) * 8 + j;
    int n = t * 16 + (lane & 15);
    float v = (k < 64) ? W2l[k * 64 + n] : W2r[(k - 64) * 64 + n];
    pw2[r] = f2b(v);
}

// ---------------- cast x (N x 8 fp32) -> bf16 rows (16 B) ----------------
__global__ __launch_bounds__(256) void xcast_kernel(const float* __restrict__ x, unsigned short* __restrict__ xb) {
    int n = blockIdx.x * 256 + threadIdx.x;
    if (n < N_NODES) {
        const float4* x4 = (const float4*)x;
        float4 v0 = x4[(size_t)n * 2], v1 = x4[(size_t)n * 2 + 1];
        uint4 p;
        p.x = (unsigned)f2b(v0.x) | ((unsigned)f2b(v0.y) << 16);
        p.y = (unsigned)f2b(v0.z) | ((unsigned)f2b(v0.w) << 16);
        p.z = (unsigned)f2b(v1.x) | ((unsigned)f2b(v1.y) << 16);
        p.w = (unsigned)f2b(v1.z) | ((unsigned)f2b(v1.w) << 16);
        ((uint4*)xb)[n] = p;
    }
}

// ---------------- layer 1: bf16 x gather, 1 edge per lane (64 in flight), register epilogue ----------------
__global__ __launch_bounds__(256) void layer1_fused(const float* __restrict__ x, const unsigned short* __restrict__ xb,
                                                    const int* __restrict__ rowptr, const int* __restrict__ esrc,
                                                    const float* __restrict__ Wl, const float* __restrict__ b,
                                                    const float* __restrict__ Wr, unsigned short* __restrict__ ob) {
    int tid = threadIdx.x;
    int sub = tid >> 6, lane = tid & 63;
    int n = blockIdx.x * 4 + sub;
    int r0 = __builtin_amdgcn_readfirstlane(rowptr[n]);
    int r1 = __builtin_amdgcn_readfirstlane(rowptr[n + 1]);
    const uint4* xb16 = (const uint4*)xb;
    float a[8];
#pragma unroll
    for (int j = 0; j < 8; j++) a[j] = 0.f;
    for (int e = r0 + lane; e < r1; e += 64) {     // whole row per lane; deg<=64 -> 1 iter
        uint4 v = xb16[esrc[e] >> 7];              // esrc = src*128 -> row idx = src
        a[0] += blo(v.x); a[1] += bhi(v.x);
        a[2] += blo(v.y); a[3] += bhi(v.y);
        a[4] += blo(v.z); a[5] += bhi(v.z);
        a[6] += blo(v.w); a[7] += bhi(v.w);
    }
#pragma unroll
    for (int m = 1; m <= 32; m <<= 1) {
#pragma unroll
        for (int j = 0; j < 8; j++) a[j] += __shfl_xor(a[j], m);
    }
    float invn = 1.0f / fmaxf((float)(r1 - r0), 1.0f);
    float al = 0.f, ar = 0.f;
#pragma unroll
    for (int kk = 0; kk < 8; kk++) {
        al += a[kk] * Wl[kk * 64 + lane];
        ar += x[(size_t)n * 8 + kk] * Wr[kk * 64 + lane];   // n wave-uniform -> scalar loads
    }
    ob[(size_t)n * 64 + lane] = f2b(fmaxf(al * invn + b[lane] + ar, 0.0f));
}

// ---------------- gather-mean only: bf16 rows, 8 edges/instr, 24 in flight ----------------
__global__ __launch_bounds__(256) void agg_kernel(const unsigned short* __restrict__ hb,
                                                  const int* __restrict__ rowptr,
                                                  const int* __restrict__ esrc,
                                                  unsigned short* __restrict__ aggb) {
    int tid = threadIdx.x;
    int sub = tid >> 6, lane = tid & 63;
    int grp = lane >> 3, q = lane & 7;
    int n = blockIdx.x * 4 + sub;
    int r0 = __builtin_amdgcn_readfirstlane(rowptr[n]);
    int r1 = __builtin_amdgcn_readfirstlane(rowptr[n + 1]);
    const uint4* h16 = (const uint4*)hb;
    uint4 v[3];
#pragma unroll
    for (int c = 0; c < 3; c++) {
        uint4 vv; vv.x = 0u; vv.y = 0u; vv.z = 0u; vv.w = 0u;
        int idx = r0 + 8 * c + grp;
        if (idx < r1) {
            int off = esrc[idx];
            vv = h16[(off >> 4) + q];
        }
        v[c] = vv;
    }
    float a[8];
#pragma unroll
    for (int j = 0; j < 8; j++) a[j] = 0.f;
#pragma unroll
    for (int c = 0; c < 3; c++) {
        a[0] += blo(v[c].x); a[1] += bhi(v[c].x);
        a[2] += blo(v[c].y); a[3] += bhi(v[c].y);
        a[4] += blo(v[c].z); a[5] += bhi(v[c].z);
        a[6] += blo(v[c].w); a[7] += bhi(v[c].w);
    }
    for (int e = r0 + 24; e < r1; e += 8) {
        int idx = e + grp;
        if (idx < r1) {
            int off = esrc[idx];
            uint4 vv = h16[(off >> 4) + q];
            a[0] += blo(vv.x); a[1] += bhi(vv.x);
            a[2] += blo(vv.y); a[3] += bhi(vv.y);
            a[4] += blo(vv.z); a[5] += bhi(vv.z);
            a[6] += blo(vv.w); a[7] += bhi(vv.w);
        }
    }
#pragma unroll
    for (int j = 0; j < 8; j++) {
        a[j] += __shfl_xor(a[j], 8);
        a[j] += __shfl_xor(a[j], 16);
        a[j] += __shfl_xor(a[j], 32);
    }
    if (grp == 0) {
        float invn = 1.0f / fmaxf((float)(r1 - r0), 1.0f);
        uint4 p;
        p.x = (unsigned)f2b(a[0] * invn) | ((unsigned)f2b(a[1] * invn) << 16);
        p.y = (unsigned)f2b(a[2] * invn) | ((unsigned)f2b(a[3] * invn) << 16);
        p.z = (unsigned)f2b(a[4] * invn) | ((unsigned)f2b(a[5] * invn) << 16);
        p.w = (unsigned)f2b(a[6] * invn) | ((unsigned)f2b(a[7] * invn) << 16);
        ((uint4*)aggb)[(size_t)n * 8 + q] = p;
    }
}

// ---------------- layer-3 gather + pooled accumulate: A[g] += mean_neighbors(h2[n]) ----------------
__global__ __launch_bounds__(256) void aggpool3(const unsigned short* __restrict__ hb,
                                                const int* __restrict__ rowptr,
                                                const int* __restrict__ esrc,
                                                const int* __restrict__ batch, float* __restrict__ A) {
    __shared__ float sa[4][64];
    __shared__ int sbat[4];
    int tid = threadIdx.x;
    int sub = tid >> 6, lane = tid & 63;
    int grp = lane >> 3, q = lane & 7;
    int n = blockIdx.x * 4 + sub;
    int r0 = __builtin_amdgcn_readfirstlane(rowptr[n]);
    int r1 = __builtin_amdgcn_readfirstlane(rowptr[n + 1]);
    const uint4* h16 = (const uint4*)hb;
    uint4 v[3];
#pragma unroll
    for (int c = 0; c < 3; c++) {
        uint4 vv; vv.x = 0u; vv.y = 0u; vv.z = 0u; vv.w = 0u;
        int idx = r0 + 8 * c + grp;
        if (idx < r1) {
            int off = esrc[idx];
            vv = h16[(off >> 4) + q];
        }
        v[c] = vv;
    }
    float a[8];
#pragma unroll
    for (int j = 0; j < 8; j++) a[j] = 0.f;
#pragma unroll
    for (int c = 0; c < 3; c++) {
        a[0] += blo(v[c].x); a[1] += bhi(v[c].x);
        a[2] += blo(v[c].y); a[3] += bhi(v[c].y);
        a[4] += blo(v[c].z); a[5] += bhi(v[c].z);
        a[6] += blo(v[c].w); a[7] += bhi(v[c].w);
    }
    for (int e = r0 + 24; e < r1; e += 8) {
        int idx = e + grp;
        if (idx < r1) {
            int off = esrc[idx];
            uint4 vv = h16[(off >> 4) + q];
            a[0] += blo(vv.x); a[1] += bhi(vv.x);
            a[2] += blo(vv.y); a[3] += bhi(vv.y);
            a[4] += blo(vv.z); a[5] += bhi(vv.z);
            a[6] += blo(vv.w); a[7] += bhi(vv.w);
        }
    }
#pragma unroll
    for (int j = 0; j < 8; j++) {
        a[j] += __shfl_xor(a[j], 8);
        a[j] += __shfl_xor(a[j], 16);
        a[j] += __shfl_xor(a[j], 32);
    }
    if (lane == 0) sbat[sub] = batch[n];
    if (grp == 0) {
        float invn = 1.0f / fmaxf((float)(r1 - r0), 1.0f);
#pragma unroll
        for (int j = 0; j < 8; j++) sa[sub][q * 8 + j] = a[j] * invn;
    }
    __syncthreads();
    if (sub == 0) {                // sorted batch: block covers 1..4 graphs
        int b0 = sbat[0], b3v = sbat[3];
        if (b0 == b3v) {
            float s = sa[0][lane] + sa[1][lane] + sa[2][lane] + sa[3][lane];
            atomicAdd(&A[b0 * 64 + lane], s);
        } else {
            float acc = sa[0][lane]; int cur = b0;
#pragma unroll
            for (int i = 1; i < 4; i++) {
                int bi = sbat[i];
                if (bi != cur) { atomicAdd(&A[cur * 64 + lane], acc); cur = bi; acc = 0.f; }
                acc += sa[i][lane];
            }
            atomicAdd(&A[cur * 64 + lane], acc);
        }
    }
}

// ---------------- MFMA GEMM: out = [agg | self] @ W' + b, per 16-node tile one wave ----------------
template <bool RELU>
__global__ __launch_bounds__(256) void gemm_kernel(const unsigned short* __restrict__ aggb,
                                                   const unsigned short* __restrict__ selfb,
                                                   const unsigned short* __restrict__ pw,
                                                   const float* __restrict__ bias,
                                                   unsigned short* __restrict__ outb) {
    int tile = (blockIdx.x * 256 + threadIdx.x) >> 6;
    if (tile >= N_NODES / 16) return;
    int lane = threadIdx.x & 63;
    int col = lane & 15, quad = lane >> 4;
    int m = tile * 16 + col;
    const uint4* arow = (const uint4*)(aggb + (size_t)m * 64);
    const uint4* srow = (const uint4*)(selfb + (size_t)m * 64);
    uint4 aa[4];
    aa[0] = arow[quad];
    aa[1] = arow[4 + quad];
    aa[2] = srow[quad];
    aa[3] = srow[4 + quad];
    const uint4* pwv = (const uint4*)pw;
    f32x4 acc[4] = {{0.f,0.f,0.f,0.f},{0.f,0.f,0.f,0.f},{0.f,0.f,0.f,0.f},{0.f,0.f,0.f,0.f}};
    union U { uint4 u; bf16x8 b; };
#pragma unroll
    for (int s = 0; s < 4; s++) {
        U a; a.u = aa[s];
#pragma unroll
        for (int t = 0; t < 4; t++) {
            U bb; bb.u = pwv[(s * 4 + t) * 64 + lane];
            acc[t] = __builtin_amdgcn_mfma_f32_16x16x32_bf16(a.b, bb.b, acc[t], 0, 0, 0);
        }
    }
#pragma unroll
    for (int t = 0; t < 4; t++) {
        float bi = bias[t * 16 + col];
#pragma unroll
        for (int i = 0; i < 4; i++) {
            int node = tile * 16 + quad * 4 + i;
            float v = acc[t][i] + bi;
            if (RELU) v = fmaxf(v, 0.0f);
            outb[(size_t)node * 64 + t * 16 + col] = f2b(v);
        }
    }
}

// ---------------- poolB: B[g] = sum h2 rows, cnt[g] = node count (sorted batch) ----------------
__global__ __launch_bounds__(256) void poolB_kernel(const unsigned short* __restrict__ hb,
                                                    const int* __restrict__ batch,
                                                    float* __restrict__ B, float* __restrict__ cntf) {
    int d = threadIdx.x & 63;
    int grp = threadIdx.x >> 6;
    int n0 = blockIdx.x * 256;
    int cur = -1; float acc = 0.f; int ac = 0;
    for (int i = grp; i < 256; i += 4) {
        int n = n0 + i;
        if (n >= N_NODES) break;
        int bb = batch[n];
        if (bb != cur) {
            if (cur >= 0) {
                atomicAdd(&B[cur * 64 + d], acc);
                if (d == 0) atomicAdd(&cntf[cur], (float)ac);
            }
            cur = bb; acc = 0.f; ac = 0;
        }
        acc += b2f(hb[(size_t)n * 64 + d]);
        ac++;
    }
    if (cur >= 0) {
        atomicAdd(&B[cur * 64 + d], acc);
        if (d == 0) atomicAdd(&cntf[cur], (float)ac);
    }
}

// ---------------- head: g = A@W3l + cnt*b3 + B@W3r, then relu(g@Wc1+bc1)@Wc2+bc2 ----------------
__global__ __launch_bounds__(256) void head2_kernel(const float* __restrict__ A, const float* __restrict__ B,
                                                    const float* __restrict__ cntf,
                                                    const float* __restrict__ W3l, const float* __restrict__ b3,
                                                    const float* __restrict__ W3r,
                                                    const float* __restrict__ Wc1, const float* __restrict__ bc1,
                                                    const float* __restrict__ Wc2, const float* __restrict__ bc2,
                                                    float* __restrict__ out) {
    __shared__ float sA[4][64], sB[4][64], sh3[4][64];
    int tid = threadIdx.x, sub = tid >> 6, lane = tid & 63;
    int gid = blockIdx.x * 4 + sub;
    sA[sub][lane] = A[gid * 64 + lane];
    sB[sub][lane] = B[gid * 64 + lane];
    float cg = cntf[gid];
    __syncthreads();
    float v = cg * b3[lane];
#pragma unroll 8
    for (int k = 0; k < 64; k++) {
        v += sA[sub][k] * W3l[k * 64 + lane] + sB[sub][k] * W3r[k * 64 + lane];
    }
    sh3[sub][lane] = v;
    __syncthreads();
    int j = lane & 31, kh = lane >> 5;
    float a = 0.f;
#pragma unroll
    for (int kk = 0; kk < 32; kk++) {
        int k = kh * 32 + kk;
        a += sh3[sub][k] * Wc1[k * 32 + j];
    }
    a += __shfl_xor(a, 32);
    float contrib = (lane < 32) ? fmaxf(a + bc1[j], 0.0f) * Wc2[j] : 0.0f;
    contrib += __shfl_xor(contrib, 16);
    contrib += __shfl_xor(contrib, 8);
    contrib += __shfl_xor(contrib, 4);
    contrib += __shfl_xor(contrib, 2);
    contrib += __shfl_xor(contrib, 1);
    if (lane == 0) out[gid] = contrib + bc2[0];
}

extern "C" void kernel_launch(void* const* d_in, const int* in_sizes, int n_in,
                              void* d_out, int out_size, void* d_ws, size_t ws_size,
                              hipStream_t stream) {
    const float* x   = (const float*)d_in[0];
    const int*   ei  = (const int*)d_in[1];
    const int*   bat = (const int*)d_in[2];
    const float* W1l = (const float*)d_in[3];
    const float* b1  = (const float*)d_in[4];
    const float* W1r = (const float*)d_in[5];
    const float* W2l = (const float*)d_in[6];
    const float* b2  = (const float*)d_in[7];
    const float* W2r = (const float*)d_in[8];
    const float* W3l = (const float*)d_in[9];
    const float* b3  = (const float*)d_in[10];
    const float* W3r = (const float*)d_in[11];
    const float* Wc1 = (const float*)d_in[12];
    const float* bc1 = (const float*)d_in[13];
    const float* Wc2 = (const float*)d_in[14];
    const float* bc2 = (const float*)d_in[15];

    float* ws = (float*)d_ws;
    // ---- workspace layout (float offsets) ----
    int*    rowptr = (int*)(ws);                              // [0, 100352)
    int*    esrc   = (int*)(ws + 100352);                     // [100352, 1300480)
    float*  A      = ws + 1300480;                            // 16384
    float*  B      = ws + 1316864;                            // 16384
    float*  cntf   = ws + 1333248;                            // 256
    unsigned short* pw2 = (unsigned short*)(ws + 1333504);    // 8192 bf16
    unsigned short* xb  = (unsigned short*)(ws + 1337600);    // N*8 bf16 = 400000 shorts
    unsigned short* hb1 = (unsigned short*)(ws + 1737728);    // N*64 bf16 = 3.2M floats
    unsigned short* hb2 = (unsigned short*)(ws + 4937728);
    unsigned short* agX = (unsigned short*)(ws + 8137728);
    int*    ebuf   = (int*)(ws + 11337728);                   // 1200000
    int*    histm  = (int*)(ws + 12537728);                   // 38416
    int*    bstart = (int*)(ws + 12576144);                   // 393

    // zero A,B,cnt in one shot (contiguous 33024 floats)
    hipMemsetAsync(A, 0, (size_t)33024 * 4, stream);

    bucketA<<<EBLK, 256, 0, stream>>>(ei, histm);
    bucketB<<<1, 512, 0, stream>>>(histm, bstart);
    bucketC<<<EBLK, 256, 0, stream>>>(ei, histm, ebuf);
    bucketD<<<NBUCK, 256, 0, stream>>>(ebuf, bstart, rowptr, esrc);
    prepack_kernel<<<32, 256, 0, stream>>>(W2l, W2r, pw2);
    xcast_kernel<<<(N_NODES + 255) / 256, 256, 0, stream>>>(x, xb);

    layer1_fused<<<N_NODES / 4, 256, 0, stream>>>(x, xb, rowptr, esrc, W1l, b1, W1r, hb1);

    agg_kernel<<<N_NODES / 4, 256, 0, stream>>>(hb1, rowptr, esrc, agX);
    gemm_kernel<true><<<(N_NODES / 16 + 3) / 4, 256, 0, stream>>>(agX, hb1, pw2, b2, hb2);

    aggpool3<<<N_NODES / 4, 256, 0, stream>>>(hb2, rowptr, esrc, bat, A);
    poolB_kernel<<<(N_NODES + 255) / 256, 256, 0, stream>>>(hb2, bat, B, cntf);

    head2_kernel<<<N_GRAPHS / 4, 256, 0, stream>>>(A, B, cntf, W3l, b3, W3r, Wc1, bc1, Wc2, bc2,
                                                   (float*)d_out);
}

// Round 11
// 324.497 us; speedup vs baseline: 1.0408x; 1.0408x over previous
//
#include <hip/hip_runtime.h>

#define N_NODES 100000
#define N_EDGES 1200000
#define N_GRAPHS 256
#define NBUCK 392            // buckets of 256 nodes: 392*256 = 100352 >= N
#define EBLK 98              // edge-pass blocks
#define EPB 12245            // ceil(E/98)
#define DCAP 4608            // max edges per bucket handled in LDS (mean 3072, sd 55)

typedef __attribute__((ext_vector_type(8))) short bf16x8;
typedef __attribute__((ext_vector_type(4))) float f32x4;

// ---- bf16 helpers (fp32 <-> bf16 as ushort, RNE) ----
__device__ inline unsigned short f2b(float f) {
    union { float f; unsigned u; } c; c.f = f;
    unsigned u = c.u;
    u += 0x7fff + ((u >> 16) & 1);
    return (unsigned short)(u >> 16);
}
__device__ inline float blo(unsigned u) { union { unsigned i; float f; } c; c.i = u << 16; return c.f; }
__device__ inline float bhi(unsigned u) { union { unsigned i; float f; } c; c.i = u & 0xffff0000u; return c.f; }
__device__ inline float b2f(unsigned short h) { union { unsigned i; float f; } c; c.i = ((unsigned)h) << 16; return c.f; }

// ---------------- bucket phase A: per-(bucket, block) histogram ----------------
__global__ __launch_bounds__(256) void bucketA(const int* __restrict__ ei, int* __restrict__ histm) {
    __shared__ int h[NBUCK];
    int k = blockIdx.x, tid = threadIdx.x;
    for (int t = tid; t < NBUCK; t += 256) h[t] = 0;
    __syncthreads();
    int e0 = k * EPB, e1 = min(e0 + EPB, N_EDGES);
    for (int e = e0 + tid; e < e1; e += 256) {
        int dd = ei[N_EDGES + e];
        atomicAdd(&h[dd >> 8], 1);
    }
    __syncthreads();
    for (int t = tid; t < NBUCK; t += 256) histm[t * EBLK + k] = h[t];
}

// ---------------- phase B: scan histm -> per-(bucket,block) start offsets + bucket starts ----------------
__global__ __launch_bounds__(512) void bucketB(int* __restrict__ histm, int* __restrict__ bstart) {
    __shared__ int sb[512];
    int tid = threadIdx.x;
    int tot = 0;
    if (tid < NBUCK) {
        for (int k = 0; k < EBLK; k++) tot += histm[tid * EBLK + k];
    }
    sb[tid] = tot;
    __syncthreads();
    int acc = tot;
    for (int off = 1; off < 512; off <<= 1) {
        int v = (tid >= off) ? sb[tid - off] : 0;
        __syncthreads();
        sb[tid] = acc = acc + v;
        __syncthreads();
    }
    int excl = acc - tot;
    if (tid < NBUCK) {
        bstart[tid] = excl;
        int run = excl;
        for (int k = 0; k < EBLK; k++) {
            int v = histm[tid * EBLK + k];
            histm[tid * EBLK + k] = run;
            run += v;
        }
    }
    if (tid == 0) bstart[NBUCK] = N_EDGES;
}

// ---------------- phase C: scatter packed (src<<8 | dstlow) into bucket-grouped ebuf ----------------
__global__ __launch_bounds__(256) void bucketC(const int* __restrict__ ei, const int* __restrict__ histm,
                                               int* __restrict__ ebuf) {
    __shared__ int cur[NBUCK];
    int k = blockIdx.x, tid = threadIdx.x;
    for (int t = tid; t < NBUCK; t += 256) cur[t] = histm[t * EBLK + k];
    __syncthreads();
    int e0 = k * EPB, e1 = min(e0 + EPB, N_EDGES);
    for (int e = e0 + tid; e < e1; e += 256) {
        int ss = ei[e];
        int dd = ei[N_EDGES + e];
        int pos = atomicAdd(&cur[dd >> 8], 1);
        ebuf[pos] = (ss << 8) | (dd & 255);
    }
}

// ---------------- phase D: per-bucket counting sort -> rowptr + esrc (coalesced writes) ----------------
__global__ __launch_bounds__(256) void bucketD(const int* __restrict__ ebuf, const int* __restrict__ bstart,
                                               int* __restrict__ rowptr, int* __restrict__ esrc) {
    __shared__ int ecache[DCAP];
    __shared__ int stage[DCAP];
    __shared__ int hist[256], off[256];
    int b = blockIdx.x, tid = threadIdx.x;
    int seg0 = bstart[b], seg1 = bstart[b + 1];
    int cnt = seg1 - seg0;
    hist[tid] = 0;
    int lim = min(cnt, DCAP);
    for (int i = tid; i < lim; i += 256) ecache[i] = ebuf[seg0 + i];
    __syncthreads();
    for (int i = tid; i < cnt; i += 256) {
        int p = (i < DCAP) ? ecache[i] : ebuf[seg0 + i];
        atomicAdd(&hist[p & 255], 1);
    }
    __syncthreads();
    int v = hist[tid];
    off[tid] = v;
    __syncthreads();
    int acc = v;
    for (int o = 1; o < 256; o <<= 1) {
        int t = (tid >= o) ? off[tid - o] : 0;
        __syncthreads();
        off[tid] = acc = acc + t;
        __syncthreads();
    }
    int excl = acc - v;
    rowptr[b * 256 + tid] = seg0 + excl;
    off[tid] = excl;
    __syncthreads();
    if (cnt <= DCAP) {
        for (int i = tid; i < cnt; i += 256) {
            int p = ecache[i];
            int pos = atomicAdd(&off[p & 255], 1);
            stage[pos] = (p >> 8) << 7;    // pre-scaled byte offset (bf16 64-dim row = 128 B)
        }
        __syncthreads();
        for (int i = tid; i < cnt; i += 256) esrc[seg0 + i] = stage[i];
    } else {                               // correctness fallback, never in practice
        for (int i = tid; i < cnt; i += 256) {
            int p = (i < DCAP) ? ecache[i] : ebuf[seg0 + i];
            int pos = atomicAdd(&off[p & 255], 1);
            esrc[seg0 + pos] = (p >> 8) << 7;
        }
    }
}

// ---------------- prepack W' = [W2l;W2r] (128x64) into MFMA B-fragment order, bf16 ----------------
__global__ __launch_bounds__(256) void prepack_kernel(const float* __restrict__ W2l, const float* __restrict__ W2r,
                                                      unsigned short* __restrict__ pw2) {
    int r = blockIdx.x * 256 + threadIdx.x;    // 8192 total
    int j = r & 7, lane = (r >> 3) & 63, t = (r >> 9) & 3, s = (r >> 11) & 3;
    int k = s * 32 + (lane >> 4) * 8 + j;
    int n = t * 16 + (lane & 15);
    float v = (k < 64) ? W2l[k * 64 + n] : W2r[(k - 64) * 64 + n];
    pw2[r] = f2b(v);
}

// ---------------- cast x (N x 8 fp32) -> bf16 rows (16 B) ----------------
__global__ __launch_bounds__(256) void xcast_kernel(const float* __restrict__ x, unsigned short* __restrict__ xb) {
    int n = blockIdx.x * 256 + threadIdx.x;
    if (n < N_NODES) {
        const float4* x4 = (const float4*)x;
        float4 v0 = x4[(size_t)n * 2], v1 = x4[(size_t)n * 2 + 1];
        uint4 p;
        p.x = (unsigned)f2b(v0.x) | ((unsigned)f2b(v0.y) << 16);
        p.y = (unsigned)f2b(v0.z) | ((unsigned)f2b(v0.w) << 16);
        p.z = (unsigned)f2b(v1.x) | ((unsigned)f2b(v1.y) << 16);
        p.w = (unsigned)f2b(v1.z) | ((unsigned)f2b(v1.w) << 16);
        ((uint4*)xb)[n] = p;
    }
}

// ---------------- layer 1: wave/node, 16 edges x 4 uint-lanes, 32 edges in flight ----------------
__global__ __launch_bounds__(256) void layer1_fused(const float* __restrict__ x, const unsigned short* __restrict__ xb,
                                                    const int* __restrict__ rowptr, const int* __restrict__ esrc,
                                                    const float* __restrict__ Wl, const float* __restrict__ b,
                                                    const float* __restrict__ Wr, unsigned short* __restrict__ ob) {
    __shared__ float sa[4][8], sx[4][8];
    int tid = threadIdx.x;
    int sub = tid >> 6, lane = tid & 63;
    int grp = lane >> 2, q = lane & 3;             // 16 edge-groups x 4 uint-lanes (4 B each)
    int n = blockIdx.x * 4 + sub;
    int r0 = __builtin_amdgcn_readfirstlane(rowptr[n]);
    int r1 = __builtin_amdgcn_readfirstlane(rowptr[n + 1]);
    const unsigned* xbu = (const unsigned*)xb;     // x row = 16 B = 4 uints
    float a0 = 0.f, a1 = 0.f;
#pragma unroll
    for (int c = 0; c < 2; c++) {                  // 32 edges in flight
        int idx = r0 + 16 * c + grp;
        if (idx < r1) {
            unsigned v = xbu[(esrc[idx] >> 5) + q];    // (src*128)>>5 = src*4
            a0 += blo(v); a1 += bhi(v);
        }
    }
    for (int e = r0 + 32; e < r1; e += 16) {       // rare tail (deg > 32)
        int idx = e + grp;
        if (idx < r1) {
            unsigned v = xbu[(esrc[idx] >> 5) + q];
            a0 += blo(v); a1 += bhi(v);
        }
    }
#pragma unroll
    for (int m = 4; m <= 32; m <<= 1) {            // reduce over 16 edge-groups
        a0 += __shfl_xor(a0, m);
        a1 += __shfl_xor(a1, m);
    }
    if (lane < 4) { sa[sub][2 * lane] = a0; sa[sub][2 * lane + 1] = a1; }
    if (lane >= 8 && lane < 16) sx[sub][lane - 8] = x[(size_t)n * 8 + (lane - 8)];
    __syncthreads();
    float invn = 1.0f / fmaxf((float)(r1 - r0), 1.0f);
    float al = 0.f, ar = 0.f;
#pragma unroll
    for (int kk = 0; kk < 8; kk++) {
        al += sa[sub][kk] * Wl[kk * 64 + lane];
        ar += sx[sub][kk] * Wr[kk * 64 + lane];
    }
    ob[(size_t)n * 64 + lane] = f2b(fmaxf(al * invn + b[lane] + ar, 0.0f));
}

// ---------------- gather-mean only: bf16 rows, 8 edges/instr, 24 in flight ----------------
__global__ __launch_bounds__(256) void agg_kernel(const unsigned short* __restrict__ hb,
                                                  const int* __restrict__ rowptr,
                                                  const int* __restrict__ esrc,
                                                  unsigned short* __restrict__ aggb) {
    int tid = threadIdx.x;
    int sub = tid >> 6, lane = tid & 63;
    int grp = lane >> 3, q = lane & 7;
    int n = blockIdx.x * 4 + sub;
    int r0 = __builtin_amdgcn_readfirstlane(rowptr[n]);
    int r1 = __builtin_amdgcn_readfirstlane(rowptr[n + 1]);
    const uint4* h16 = (const uint4*)hb;
    uint4 v[3];
#pragma unroll
    for (int c = 0; c < 3; c++) {
        uint4 vv; vv.x = 0u; vv.y = 0u; vv.z = 0u; vv.w = 0u;
        int idx = r0 + 8 * c + grp;
        if (idx < r1) {
            int off = esrc[idx];
            vv = h16[(off >> 4) + q];
        }
        v[c] = vv;
    }
    float a[8];
#pragma unroll
    for (int j = 0; j < 8; j++) a[j] = 0.f;
#pragma unroll
    for (int c = 0; c < 3; c++) {
        a[0] += blo(v[c].x); a[1] += bhi(v[c].x);
        a[2] += blo(v[c].y); a[3] += bhi(v[c].y);
        a[4] += blo(v[c].z); a[5] += bhi(v[c].z);
        a[6] += blo(v[c].w); a[7] += bhi(v[c].w);
    }
    for (int e = r0 + 24; e < r1; e += 8) {
        int idx = e + grp;
        if (idx < r1) {
            int off = esrc[idx];
            uint4 vv = h16[(off >> 4) + q];
            a[0] += blo(vv.x); a[1] += bhi(vv.x);
            a[2] += blo(vv.y); a[3] += bhi(vv.y);
            a[4] += blo(vv.z); a[5] += bhi(vv.z);
            a[6] += blo(vv.w); a[7] += bhi(vv.w);
        }
    }
#pragma unroll
    for (int j = 0; j < 8; j++) {
        a[j] += __shfl_xor(a[j], 8);
        a[j] += __shfl_xor(a[j], 16);
        a[j] += __shfl_xor(a[j], 32);
    }
    if (grp == 0) {
        float invn = 1.0f / fmaxf((float)(r1 - r0), 1.0f);
        uint4 p;
        p.x = (unsigned)f2b(a[0] * invn) | ((unsigned)f2b(a[1] * invn) << 16);
        p.y = (unsigned)f2b(a[2] * invn) | ((unsigned)f2b(a[3] * invn) << 16);
        p.z = (unsigned)f2b(a[4] * invn) | ((unsigned)f2b(a[5] * invn) << 16);
        p.w = (unsigned)f2b(a[6] * invn) | ((unsigned)f2b(a[7] * invn) << 16);
        ((uint4*)aggb)[(size_t)n * 8 + q] = p;
    }
}

// ---------------- layer-3 gather + pooled accumulate: A[g] += mean_neighbors(h2[n]) ----------------
__global__ __launch_bounds__(256) void aggpool3(const unsigned short* __restrict__ hb,
                                                const int* __restrict__ rowptr,
                                                const int* __restrict__ esrc,
                                                const int* __restrict__ batch, float* __restrict__ A) {
    __shared__ float sa[4][64];
    __shared__ int sbat[4];
    int tid = threadIdx.x;
    int sub = tid >> 6, lane = tid & 63;
    int grp = lane >> 3, q = lane & 7;
    int n = blockIdx.x * 4 + sub;
    int r0 = __builtin_amdgcn_readfirstlane(rowptr[n]);
    int r1 = __builtin_amdgcn_readfirstlane(rowptr[n + 1]);
    const uint4* h16 = (const uint4*)hb;
    uint4 v[3];
#pragma unroll
    for (int c = 0; c < 3; c++) {
        uint4 vv; vv.x = 0u; vv.y = 0u; vv.z = 0u; vv.w = 0u;
        int idx = r0 + 8 * c + grp;
        if (idx < r1) {
            int off = esrc[idx];
            vv = h16[(off >> 4) + q];
        }
        v[c] = vv;
    }
    float a[8];
#pragma unroll
    for (int j = 0; j < 8; j++) a[j] = 0.f;
#pragma unroll
    for (int c = 0; c < 3; c++) {
        a[0] += blo(v[c].x); a[1] += bhi(v[c].x);
        a[2] += blo(v[c].y); a[3] += bhi(v[c].y);
        a[4] += blo(v[c].z); a[5] += bhi(v[c].z);
        a[6] += blo(v[c].w); a[7] += bhi(v[c].w);
    }
    for (int e = r0 + 24; e < r1; e += 8) {
        int idx = e + grp;
        if (idx < r1) {
            int off = esrc[idx];
            uint4 vv = h16[(off >> 4) + q];
            a[0] += blo(vv.x); a[1] += bhi(vv.x);
            a[2] += blo(vv.y); a[3] += bhi(vv.y);
            a[4] += blo(vv.z); a[5] += bhi(vv.z);
            a[6] += blo(vv.w); a[7] += bhi(vv.w);
        }
    }
#pragma unroll
    for (int j = 0; j < 8; j++) {
        a[j] += __shfl_xor(a[j], 8);
        a[j] += __shfl_xor(a[j], 16);
        a[j] += __shfl_xor(a[j], 32);
    }
    if (lane == 0) sbat[sub] = batch[n];
    if (grp == 0) {
        float invn = 1.0f / fmaxf((float)(r1 - r0), 1.0f);
#pragma unroll
        for (int j = 0; j < 8; j++) sa[sub][q * 8 + j] = a[j] * invn;
    }
    __syncthreads();
    if (sub == 0) {                // sorted batch: block covers 1..4 graphs
        int b0 = sbat[0], b3v = sbat[3];
        if (b0 == b3v) {
            float s = sa[0][lane] + sa[1][lane] + sa[2][lane] + sa[3][lane];
            atomicAdd(&A[b0 * 64 + lane], s);
        } else {
            float acc = sa[0][lane]; int cur = b0;
#pragma unroll
            for (int i = 1; i < 4; i++) {
                int bi = sbat[i];
                if (bi != cur) { atomicAdd(&A[cur * 64 + lane], acc); cur = bi; acc = 0.f; }
                acc += sa[i][lane];
            }
            atomicAdd(&A[cur * 64 + lane], acc);
        }
    }
}

// ---------------- MFMA GEMM: out = [agg | self] @ W' + b, per 16-node tile one wave ----------------
template <bool RELU>
__global__ __launch_bounds__(256) void gemm_kernel(const unsigned short* __restrict__ aggb,
                                                   const unsigned short* __restrict__ selfb,
                                                   const unsigned short* __restrict__ pw,
                                                   const float* __restrict__ bias,
                                                   unsigned short* __restrict__ outb) {
    int tile = (blockIdx.x * 256 + threadIdx.x) >> 6;
    if (tile >= N_NODES / 16) return;
    int lane = threadIdx.x & 63;
    int col = lane & 15, quad = lane >> 4;
    int m = tile * 16 + col;
    const uint4* arow = (const uint4*)(aggb + (size_t)m * 64);
    const uint4* srow = (const uint4*)(selfb + (size_t)m * 64);
    uint4 aa[4];
    aa[0] = arow[quad];
    aa[1] = arow[4 + quad];
    aa[2] = srow[quad];
    aa[3] = srow[4 + quad];
    const uint4* pwv = (const uint4*)pw;
    f32x4 acc[4] = {{0.f,0.f,0.f,0.f},{0.f,0.f,0.f,0.f},{0.f,0.f,0.f,0.f},{0.f,0.f,0.f,0.f}};
    union U { uint4 u; bf16x8 b; };
#pragma unroll
    for (int s = 0; s < 4; s++) {
        U a; a.u = aa[s];
#pragma unroll
        for (int t = 0; t < 4; t++) {
            U bb; bb.u = pwv[(s * 4 + t) * 64 + lane];
            acc[t] = __builtin_amdgcn_mfma_f32_16x16x32_bf16(a.b, bb.b, acc[t], 0, 0, 0);
        }
    }
#pragma unroll
    for (int t = 0; t < 4; t++) {
        float bi = bias[t * 16 + col];
#pragma unroll
        for (int i = 0; i < 4; i++) {
            int node = tile * 16 + quad * 4 + i;
            float v = acc[t][i] + bi;
            if (RELU) v = fmaxf(v, 0.0f);
            outb[(size_t)node * 64 + t * 16 + col] = f2b(v);
        }
    }
}

// ---------------- poolB: B[g] = sum h2 rows, cnt[g] = node count (sorted batch) ----------------
__global__ __launch_bounds__(256) void poolB_kernel(const unsigned short* __restrict__ hb,
                                                    const int* __restrict__ batch,
                                                    float* __restrict__ B, float* __restrict__ cntf) {
    int d = threadIdx.x & 63;
    int grp = threadIdx.x >> 6;
    int n0 = blockIdx.x * 256;
    int cur = -1; float acc = 0.f; int ac = 0;
    for (int i = grp; i < 256; i += 4) {
        int n = n0 + i;
        if (n >= N_NODES) break;
        int bb = batch[n];
        if (bb != cur) {
            if (cur >= 0) {
                atomicAdd(&B[cur * 64 + d], acc);
                if (d == 0) atomicAdd(&cntf[cur], (float)ac);
            }
            cur = bb; acc = 0.f; ac = 0;
        }
        acc += b2f(hb[(size_t)n * 64 + d]);
        ac++;
    }
    if (cur >= 0) {
        atomicAdd(&B[cur * 64 + d], acc);
        if (d == 0) atomicAdd(&cntf[cur], (float)ac);
    }
}

// ---------------- head: g = A@W3l + cnt*b3 + B@W3r, then relu(g@Wc1+bc1)@Wc2+bc2 ----------------
__global__ __launch_bounds__(256) void head2_kernel(const float* __restrict__ A, const float* __restrict__ B,
                                                    const float* __restrict__ cntf,
                                                    const float* __restrict__ W3l, const float* __restrict__ b3,
                                                    const float* __restrict__ W3r,
                                                    const float* __restrict__ Wc1, const float* __restrict__ bc1,
                                                    const float* __restrict__ Wc2, const float* __restrict__ bc2,
                                                    float* __restrict__ out) {
    __shared__ float sA[4][64], sB[4][64], sh3[4][64];
    int tid = threadIdx.x, sub = tid >> 6, lane = tid & 63;
    int gid = blockIdx.x * 4 + sub;
    sA[sub][lane] = A[gid * 64 + lane];
    sB[sub][lane] = B[gid * 64 + lane];
    float cg = cntf[gid];
    __syncthreads();
    float v = cg * b3[lane];
#pragma unroll 8
    for (int k = 0; k < 64; k++) {
        v += sA[sub][k] * W3l[k * 64 + lane] + sB[sub][k] * W3r[k * 64 + lane];
    }
    sh3[sub][lane] = v;
    __syncthreads();
    int j = lane & 31, kh = lane >> 5;
    float a = 0.f;
#pragma unroll
    for (int kk = 0; kk < 32; kk++) {
        int k = kh * 32 + kk;
        a += sh3[sub][k] * Wc1[k * 32 + j];
    }
    a += __shfl_xor(a, 32);
    float contrib = (lane < 32) ? fmaxf(a + bc1[j], 0.0f) * Wc2[j] : 0.0f;
    contrib += __shfl_xor(contrib, 16);
    contrib += __shfl_xor(contrib, 8);
    contrib += __shfl_xor(contrib, 4);
    contrib += __shfl_xor(contrib, 2);
    contrib += __shfl_xor(contrib, 1);
    if (lane == 0) out[gid] = contrib + bc2[0];
}

extern "C" void kernel_launch(void* const* d_in, const int* in_sizes, int n_in,
                              void* d_out, int out_size, void* d_ws, size_t ws_size,
                              hipStream_t stream) {
    const float* x   = (const float*)d_in[0];
    const int*   ei  = (const int*)d_in[1];
    const int*   bat = (const int*)d_in[2];
    const float* W1l = (const float*)d_in[3];
    const float* b1  = (const float*)d_in[4];
    const float* W1r = (const float*)d_in[5];
    const float* W2l = (const float*)d_in[6];
    const float* b2  = (const float*)d_in[7];
    const float* W2r = (const float*)d_in[8];
    const float* W3l = (const float*)d_in[9];
    const float* b3  = (const float*)d_in[10];
    const float* W3r = (const float*)d_in[11];
    const float* Wc1 = (const float*)d_in[12];
    const float* bc1 = (const float*)d_in[13];
    const float* Wc2 = (const float*)d_in[14];
    const float* bc2 = (const float*)d_in[15];

    float* ws = (float*)d_ws;
    // ---- workspace layout (float offsets) ----
    int*    rowptr = (int*)(ws);                              // [0, 100352)
    int*    esrc   = (int*)(ws + 100352);                     // [100352, 1300480)
    float*  A      = ws + 1300480;                            // 16384
    float*  B      = ws + 1316864;                            // 16384
    float*  cntf   = ws + 1333248;                            // 256
    unsigned short* pw2 = (unsigned short*)(ws + 1333504);    // 8192 bf16
    unsigned short* xb  = (unsigned short*)(ws + 1337600);    // N*8 bf16 = 400000 shorts
    unsigned short* hb1 = (unsigned short*)(ws + 1737728);    // N*64 bf16 = 3.2M floats
    unsigned short* hb2 = (unsigned short*)(ws + 4937728);
    unsigned short* agX = (unsigned short*)(ws + 8137728);
    int*    ebuf   = (int*)(ws + 11337728);                   // 1200000
    int*    histm  = (int*)(ws + 12537728);                   // 38416
    int*    bstart = (int*)(ws + 12576144);                   // 393

    // zero A,B,cnt in one shot (contiguous 33024 floats)
    hipMemsetAsync(A, 0, (size_t)33024 * 4, stream);

    bucketA<<<EBLK, 256, 0, stream>>>(ei, histm);
    bucketB<<<1, 512, 0, stream>>>(histm, bstart);
    bucketC<<<EBLK, 256, 0, stream>>>(ei, histm, ebuf);
    bucketD<<<NBUCK, 256, 0, stream>>>(ebuf, bstart, rowptr, esrc);
    prepack_kernel<<<32, 256, 0, stream>>>(W2l, W2r, pw2);
    xcast_kernel<<<(N_NODES + 255) / 256, 256, 0, stream>>>(x, xb);

    layer1_fused<<<N_NODES / 4, 256, 0, stream>>>(x, xb, rowptr, esrc, W1l, b1, W1r, hb1);

    agg_kernel<<<N_NODES / 4, 256, 0, stream>>>(hb1, rowptr, esrc, agX);
    gemm_kernel<true><<<(N_NODES / 16 + 3) / 4, 256, 0, stream>>>(agX, hb1, pw2, b2, hb2);

    aggpool3<<<N_NODES / 4, 256, 0, stream>>>(hb2, rowptr, esrc, bat, A);
    poolB_kernel<<<(N_NODES + 255) / 256, 256, 0, stream>>>(hb2, bat, B, cntf);

    head2_kernel<<<N_GRAPHS / 4, 256, 0, stream>>>(A, B, cntf, W3l, b3, W3r, Wc1, bc1, Wc2, bc2,
                                                   (float*)d_out);
}